// Round 3
// baseline (1277.986 us; speedup 1.0000x reference)
//
#include <hip/hip_runtime.h>

#define T_STEPS 256
#define B_SZ    128
#define F_SZ    2500
#define H_SZ    128
#define O_SZ    2
#define KSPLIT0 1248          // 39*32; split1 covers 1252 = 40 steps (masked)
#define FLAG_WINDOW 1.25e-4   // |mem-1| < window => neuron needs fp64 recheck
#define MAX_FLAGS 16384

// ---------------- K1: transpose W1 [H][F] -> W1T [F][H]; zero flag counter ----------------
__global__ __launch_bounds__(256) void k_transpose(const float* __restrict__ W1,
                                                   float* __restrict__ W1T,
                                                   int* __restrict__ flag_count) {
    int idx = blockIdx.x * 256 + threadIdx.x;   // 320000 total
    if (idx == 0) *flag_count = 0;
    if (idx >= F_SZ * H_SZ) return;
    int k = idx >> 7;
    int h = idx & 127;
    W1T[idx] = W1[h * F_SZ + k];
}

// ---------------- K2: partial GEMM, fp32 ----------------
// grid 512: t = bid>>1, split = bid&1 (K-halves). 2 blocks/CU -> 2 waves/SIMD.
// Tile 128(b) x 128(h), K_blk 32. A-LDS: row-major float4 slots with XOR swizzle
// slot = rr*8 + (kc ^ ((rr>>2)&7)) -> conflict-free b128 writes AND reads.
// B-LDS: k-major [32][128] (natural W1T rows), conflict-free both ways.
__global__ __launch_bounds__(256, 2) void k_gemm(const float* __restrict__ x,
                                                 const float* __restrict__ W1T,
                                                 float* __restrict__ curA,
                                                 float* __restrict__ curB) {
    __shared__ float4 Alds4[128 * 8];       // 16 KB
    __shared__ float  Blds [32 * 128];      // 16 KB

    const int bid   = blockIdx.x;
    const int t     = bid >> 1;
    const int split = bid & 1;
    const int k0    = split ? KSPLIT0 : 0;
    const int kend  = split ? F_SZ : KSPLIT0;
    const int NSTEP = split ? 40 : 39;
    float* outP = split ? curB : curA;

    const int tid  = threadIdx.x;
    const int lane = tid & 63;
    const int w    = tid >> 6;
    const int wm   = w >> 1;
    const int wn   = w & 1;
    const int li   = lane & 7;
    const int lj   = lane >> 3;

    // staging assignments
    const int ac = tid & 7;          // A k-chunk (float4)
    const int ar = tid >> 3;         // A row 0..31 (+32*i)
    const int aswz = ac ^ ((ar >> 2) & 7);
    const int bn = tid & 31;         // B h-chunk (float4)
    const int bk = tid >> 5;         // B k row 0..7 (+8*i)

    float4 aV[4], bV[4];

    auto loadA = [&](int kb) {
        const int k = kb + ac * 4;
        const bool ok = (k < kend);
        #pragma unroll
        for (int i = 0; i < 4; ++i) {
            const int rr = ar + i * 32;
            if (ok) aV[i] = *(const float4*)(x + (size_t)(rr * T_STEPS + t) * F_SZ + k);
            else    aV[i] = make_float4(0.f, 0.f, 0.f, 0.f);
        }
    };
    auto loadB = [&](int kb) {
        #pragma unroll
        for (int i = 0; i < 4; ++i) {
            const int k = kb + bk + i * 8;
            if (k < kend) bV[i] = *(const float4*)(W1T + (size_t)k * H_SZ + bn * 4);
            else          bV[i] = make_float4(0.f, 0.f, 0.f, 0.f);
        }
    };
    auto storeTiles = [&]() {
        #pragma unroll
        for (int i = 0; i < 4; ++i) {
            const int rr = ar + i * 32;
            Alds4[rr * 8 + aswz] = aV[i];                       // conflict-free (2-way)
            *(float4*)(Blds + (bk + i * 8) * 128 + bn * 4) = bV[i];
        }
    };

    float acc[2][2][4][4];
    #pragma unroll
    for (int a = 0; a < 2; ++a)
        #pragma unroll
        for (int b = 0; b < 2; ++b)
            #pragma unroll
            for (int i = 0; i < 4; ++i)
                #pragma unroll
                for (int j = 0; j < 4; ++j)
                    acc[a][b][i][j] = 0.f;

    // per-thread A fragment row slot bases (8 rows)
    int abase[8];
    #pragma unroll
    for (int rh = 0; rh < 2; ++rh)
        #pragma unroll
        for (int i = 0; i < 4; ++i)
            abase[rh * 4 + i] = (wm * 64 + rh * 32 + li * 4 + i) * 8;

    const float4* Blds4 = (const float4*)Blds;
    const int bbase = wn * 16 + lj;       // float4 index within a B row (32 float4/row)

    loadA(k0);
    loadB(k0);

    #pragma unroll 1
    for (int s = 0; s < NSTEP; ++s) {
        __syncthreads();
        storeTiles();
        if (s + 1 < NSTEP) { loadA(k0 + (s + 1) * 32); loadB(k0 + (s + 1) * 32); }
        __syncthreads();

        #pragma unroll
        for (int kc = 0; kc < 8; ++kc) {
            const int kcli = kc ^ li;
            float4 av4[8];
            #pragma unroll
            for (int r = 0; r < 8; ++r) av4[r] = Alds4[abase[r] + kcli];

            #pragma unroll
            for (int dk = 0; dk < 4; ++dk) {
                const float4 bv0 = Blds4[(kc * 4 + dk) * 32 + bbase];
                const float4 bv1 = Blds4[(kc * 4 + dk) * 32 + bbase + 8];
                const float bvf[2][4] = {{bv0.x, bv0.y, bv0.z, bv0.w},
                                         {bv1.x, bv1.y, bv1.z, bv1.w}};
                #pragma unroll
                for (int rh = 0; rh < 2; ++rh)
                    #pragma unroll
                    for (int i = 0; i < 4; ++i) {
                        const float4 a4 = av4[rh * 4 + i];
                        const float af = (dk == 0) ? a4.x : (dk == 1) ? a4.y : (dk == 2) ? a4.z : a4.w;
                        #pragma unroll
                        for (int ch = 0; ch < 2; ++ch)
                            #pragma unroll
                            for (int j = 0; j < 4; ++j)
                                acc[rh][ch][i][j] = fmaf(af, bvf[ch][j], acc[rh][ch][i][j]);
                    }
            }
        }
    }

    // store partial (no bias; bias added in lif1)
    #pragma unroll
    for (int rh = 0; rh < 2; ++rh) {
        #pragma unroll
        for (int i = 0; i < 4; ++i) {
            const int r = wm * 64 + rh * 32 + li * 4 + i;
            float* outp = outP + (size_t)(t * 128 + r) * 128 + wn * 64 + lj * 4;
            *(float4*)(outp)      = make_float4(acc[rh][0][i][0], acc[rh][0][i][1],
                                                acc[rh][0][i][2], acc[rh][0][i][3]);
            *(float4*)(outp + 32) = make_float4(acc[rh][1][i][0], acc[rh][1][i][1],
                                                acc[rh][1][i][2], acc[rh][1][i][3]);
        }
    }
}

// ---------------- K3: LIF layer 1 (fp64 chain on fp32 currents) + borderline flagging ----------------
__global__ __launch_bounds__(256) void k_lif1(const float* __restrict__ curA,
                                              const float* __restrict__ curB,
                                              const float* __restrict__ b1,
                                              float* __restrict__ spk1,
                                              int* __restrict__ flag_count,
                                              int* __restrict__ flag_list) {
    const int idx = blockIdx.x * 256 + threadIdx.x;   // 0..16383 = b*128+h
    const double b1v = (double)b1[idx & 127];
    double mem = 0.0;
    bool flagged = false;
    #pragma unroll 8
    for (int t = 0; t < T_STEPS; ++t) {
        const double cur = (double)curA[t * 16384 + idx] + (double)curB[t * 16384 + idx] + b1v;
        const double rst = (mem > 1.0) ? 1.0 : 0.0;
        mem = 0.9 * mem + cur - rst;
        spk1[t * 16384 + idx] = (mem > 1.0) ? 1.0f : 0.0f;
        if (!flagged && fabs(mem - 1.0) < FLAG_WINDOW) {
            flagged = true;
            int p = atomicAdd(flag_count, 1);
            if (p < MAX_FLAGS) flag_list[p] = idx;
        }
    }
}

// ---------------- K3b: exact fp64 recompute of flagged neurons ----------------
// One wave per flagged neuron; lanes k-parallel over F, shuffle-reduce in fp64.
__global__ __launch_bounds__(256) void k_fixup(const float* __restrict__ x,
                                               const float* __restrict__ W1,
                                               const float* __restrict__ b1,
                                               float* __restrict__ spk1,
                                               const int* __restrict__ flag_count,
                                               const int* __restrict__ flag_list) {
    const int gw   = (blockIdx.x * 256 + threadIdx.x) >> 6;   // 0..511
    const int lane = threadIdx.x & 63;
    int n = *flag_count;
    if (n > MAX_FLAGS) n = MAX_FLAGS;

    for (int i = gw; i < n; i += 512) {
        const int idx = flag_list[i];
        const int b = idx >> 7;
        const int h = idx & 127;

        // W1 row h (2500 floats = 625 float4)
        float4 wv[10];
        #pragma unroll
        for (int j = 0; j < 10; ++j) {
            const int wj = lane + 64 * j;
            wv[j] = (wj < 625) ? ((const float4*)W1)[(size_t)h * 625 + wj]
                               : make_float4(0.f, 0.f, 0.f, 0.f);
        }
        const float4* xb = (const float4*)x + (size_t)b * T_STEPS * 625;

        float4 xv[10];
        #pragma unroll
        for (int j = 0; j < 10; ++j) {
            const int wj = lane + 64 * j;
            xv[j] = (wj < 625) ? xb[wj] : make_float4(0.f, 0.f, 0.f, 0.f);
        }

        double mem = 0.0;
        const double b1v = (double)b1[h];
        for (int t = 0; t < T_STEPS; ++t) {
            float4 xn[10];
            if (t + 1 < T_STEPS) {
                #pragma unroll
                for (int j = 0; j < 10; ++j) {
                    const int wj = lane + 64 * j;
                    xn[j] = (wj < 625) ? xb[(size_t)(t + 1) * 625 + wj]
                                       : make_float4(0.f, 0.f, 0.f, 0.f);
                }
            }
            double p = 0.0;
            #pragma unroll
            for (int j = 0; j < 10; ++j) {
                p = fma((double)xv[j].x, (double)wv[j].x, p);
                p = fma((double)xv[j].y, (double)wv[j].y, p);
                p = fma((double)xv[j].z, (double)wv[j].z, p);
                p = fma((double)xv[j].w, (double)wv[j].w, p);
            }
            #pragma unroll
            for (int off = 32; off >= 1; off >>= 1) p += __shfl_down(p, off);
            if (lane == 0) {
                const double cur = p + b1v;
                const double rst = (mem > 1.0) ? 1.0 : 0.0;
                mem = 0.9 * mem + cur - rst;
                spk1[t * 16384 + idx] = (mem > 1.0) ? 1.0f : 0.0f;
            }
            #pragma unroll
            for (int j = 0; j < 10; ++j) xv[j] = xn[j];
        }
    }
}

// ---------------- K4: cur2 = spk1 . W2^T + b2 (fp64) ----------------
__global__ __launch_bounds__(256) void k_cur2(const float* __restrict__ spk1,
                                              const float* __restrict__ W2,
                                              const float* __restrict__ b2,
                                              double* __restrict__ cur2) {
    const int wave = (blockIdx.x * 256 + threadIdx.x) >> 6;  // 0..32767 = t*128+b
    const int lane = threadIdx.x & 63;
    const float2 s  = *(const float2*)(spk1 + (size_t)wave * 128 + lane * 2);
    const float2 w0 = *(const float2*)(W2 + lane * 2);
    const float2 w1 = *(const float2*)(W2 + 128 + lane * 2);
    double v0 = (double)s.x * (double)w0.x + (double)s.y * (double)w0.y;
    double v1 = (double)s.x * (double)w1.x + (double)s.y * (double)w1.y;
    #pragma unroll
    for (int off = 32; off >= 1; off >>= 1) {
        v0 += __shfl_down(v0, off);
        v1 += __shfl_down(v1, off);
    }
    if (lane == 0) {
        cur2[wave * 2 + 0] = v0 + (double)b2[0];
        cur2[wave * 2 + 1] = v1 + (double)b2[1];
    }
}

// ---------------- K5: LIF layer 2 (fp64) + fp32 outputs ----------------
__global__ __launch_bounds__(256) void k_lif2(const double* __restrict__ cur2,
                                              float* __restrict__ out) {
    const int tid = threadIdx.x;
    double mem = 0.0;
    float* spk_out = out;
    float* mem_out = out + T_STEPS * B_SZ * O_SZ;
    #pragma unroll 8
    for (int t = 0; t < T_STEPS; ++t) {
        const double cur = cur2[t * 256 + tid];
        const double rst = (mem > 1.0) ? 1.0 : 0.0;
        mem = 0.9 * mem + cur - rst;
        spk_out[t * 256 + tid] = (mem > 1.0) ? 1.0f : 0.0f;
        mem_out[t * 256 + tid] = (float)mem;
    }
}

extern "C" void kernel_launch(void* const* d_in, const int* in_sizes, int n_in,
                              void* d_out, int out_size, void* d_ws, size_t ws_size,
                              hipStream_t stream) {
    const float* x  = (const float*)d_in[0];   // [128][256][2500]
    const float* W1 = (const float*)d_in[1];   // [128][2500]
    const float* b1 = (const float*)d_in[2];   // [128]
    const float* W2 = (const float*)d_in[3];   // [2][128]
    const float* b2 = (const float*)d_in[4];   // [2]
    float* out = (float*)d_out;                // 131072 floats

    char* ws = (char*)d_ws;
    float*  curA = (float*)ws;                              // 16,777,216 B
    float*  curB = (float*)(ws + 16777216);                 // 16,777,216 B
    float*  spk1 = (float*)(ws + 33554432);                 // 16,777,216 B
    float*  W1T  = (float*)(ws + 50331648);                 // 1,280,000 B (dead after gemm)
    double* cur2 = (double*)(ws + 50331648);                //   524,288 B (overlaps W1T: OK)
    int*    flag_count = (int*)(ws + 51611648);             // 4 B
    int*    flag_list  = (int*)(ws + 51611656);             // 65,536 B

    k_transpose<<<1250, 256, 0, stream>>>(W1, W1T, flag_count);
    k_gemm<<<512, 256, 0, stream>>>(x, W1T, curA, curB);
    k_lif1<<<64, 256, 0, stream>>>(curA, curB, b1, spk1, flag_count, flag_list);
    k_fixup<<<128, 256, 0, stream>>>(x, W1, b1, spk1, flag_count, flag_list);
    k_cur2<<<8192, 256, 0, stream>>>(spk1, W2, b2, cur2);
    k_lif2<<<1, 256, 0, stream>>>(cur2, out);
}

// Round 5
// 827.478 us; speedup vs baseline: 1.5444x; 1.5444x over previous
//
#include <hip/hip_runtime.h>

#define T_STEPS 256
#define B_SZ    128
#define F_SZ    2500
#define F4      625        // F_SZ / 4
#define H_SZ    128
#define O_SZ    2
#define FLAG_WINDOW 5e-5   // |mem-1| < window => fp64 recheck (mem err RMS ~3.5e-6)
#define CHUNK   12         // flagged W1 rows staged in LDS per pass (120 KB)

// ---------------- K1: transpose W1 [H][F] -> W1T [F][H]; zero per-b flag counts ----------------
__global__ __launch_bounds__(256) void k_transpose(const float* __restrict__ W1,
                                                   float* __restrict__ W1T,
                                                   int* __restrict__ nh) {
    int idx = blockIdx.x * 256 + threadIdx.x;   // 320000 total
    if (idx < B_SZ) nh[idx] = 0;
    if (idx >= F_SZ * H_SZ) return;
    int k = idx >> 7;
    int h = idx & 127;
    W1T[idx] = W1[h * F_SZ + k];
}

// ---------------- K2: cur1[t][b][h] = x[b][t][:] . W1T[:][h]  (fp32, raw dot, no bias) ----------------
// grid 512: t = bid>>1, b-half = bid&1. Tile 64(b) x 128(h), BK=32. 2 blocks/CU.
// A-LDS k-major [32][64] with row XOR swizzle (row ^ ((k>>2 & 3)<<3)): scalar staging
// writes land on 32 distinct banks (2-way = free); b128 reads stay contiguous.
// B-LDS k-major [32][128], natural float4 rows (conflict-free both directions).
__global__ __launch_bounds__(256, 2) void k_gemm(const float* __restrict__ x,
                                                 const float* __restrict__ W1T,
                                                 float* __restrict__ cur1) {
    __shared__ float Alds[32 * 64];    // 8 KB
    __shared__ float Blds[32 * 128];   // 16 KB

    const int t   = blockIdx.x >> 1;
    const int b0  = (blockIdx.x & 1) * 64;
    const int tid = threadIdx.x;
    const int tc  = tid & 15;          // h-group: cols tc*4 and 64+tc*4
    const int tr  = tid >> 4;          // b-group: rows tr*4 .. tr*4+3

    // staging assignments
    const int ac = tid & 7;            // A k-chunk (float4 along k)
    const int ar = tid >> 3;           // A row (0..31; also +32)
    const int aswz = (ac & 3) << 3;    // = ((k>>2)&3)<<3 for k in this chunk
    const int bn = tid & 31;           // B h float4
    const int bk = tid >> 5;           // B k row (0..7; +8i)

    float4 aV[2], bV[4];

    auto loadA = [&](int kb) {
        const int k = kb + ac * 4;
        const bool ok = (k < F_SZ);
        const float* p0 = x + ((size_t)(b0 + ar) * T_STEPS + t) * F_SZ + k;
        const float* p1 = x + ((size_t)(b0 + ar + 32) * T_STEPS + t) * F_SZ + k;
        aV[0] = ok ? *(const float4*)p0 : make_float4(0.f, 0.f, 0.f, 0.f);
        aV[1] = ok ? *(const float4*)p1 : make_float4(0.f, 0.f, 0.f, 0.f);
    };
    auto loadB = [&](int kb) {
        #pragma unroll
        for (int i = 0; i < 4; ++i) {
            const int k = kb + bk + 8 * i;
            bV[i] = (k < F_SZ) ? *(const float4*)(W1T + (size_t)k * H_SZ + bn * 4)
                               : make_float4(0.f, 0.f, 0.f, 0.f);
        }
    };
    auto stage = [&]() {
        const float* a0 = (const float*)&aV[0];
        const float* a1 = (const float*)&aV[1];
        #pragma unroll
        for (int c = 0; c < 4; ++c) {
            Alds[(ac * 4 + c) * 64 + (ar ^ aswz)]        = a0[c];
            Alds[(ac * 4 + c) * 64 + ((ar + 32) ^ aswz)] = a1[c];
        }
        #pragma unroll
        for (int i = 0; i < 4; ++i)
            *(float4*)(Blds + (bk + 8 * i) * 128 + bn * 4) = bV[i];
    };

    float acc0[4][4], acc1[4][4];
    #pragma unroll
    for (int i = 0; i < 4; ++i)
        #pragma unroll
        for (int j = 0; j < 4; ++j) { acc0[i][j] = 0.f; acc1[i][j] = 0.f; }

    const int NSTEP = 79;              // ceil(2500/32), tail masked
    loadA(0);
    loadB(0);

    #pragma unroll 1
    for (int s = 0; s < NSTEP; ++s) {
        __syncthreads();
        stage();
        if (s + 1 < NSTEP) { loadA((s + 1) * 32); loadB((s + 1) * 32); }
        __syncthreads();

        #pragma unroll
        for (int k = 0; k < 32; ++k) {
            const float4 a4  = *(const float4*)(Alds + k * 64 + ((tr * 4) ^ (((k >> 2) & 3) << 3)));
            const float4 b4a = *(const float4*)(Blds + k * 128 + tc * 4);
            const float4 b4b = *(const float4*)(Blds + k * 128 + 64 + tc * 4);
            const float* af = (const float*)&a4;
            const float* ba = (const float*)&b4a;
            const float* bb = (const float*)&b4b;
            #pragma unroll
            for (int i = 0; i < 4; ++i)
                #pragma unroll
                for (int j = 0; j < 4; ++j) {
                    acc0[i][j] = fmaf(af[i], ba[j], acc0[i][j]);
                    acc1[i][j] = fmaf(af[i], bb[j], acc1[i][j]);
                }
        }
    }

    #pragma unroll
    for (int i = 0; i < 4; ++i) {
        const int bg = b0 + tr * 4 + i;
        float* op = cur1 + ((size_t)t * B_SZ + bg) * H_SZ + tc * 4;
        *(float4*)op        = make_float4(acc0[i][0], acc0[i][1], acc0[i][2], acc0[i][3]);
        *(float4*)(op + 64) = make_float4(acc1[i][0], acc1[i][1], acc1[i][2], acc1[i][3]);
    }
}

// ---------------- K3: LIF1 (fp64 chain on fp32 dots + bias), spikes -> ballot bitmasks ----------------
// Thread per (b,h); block = 2 b x 128 h; wave = 64 h of one b. Flags near-threshold neurons.
__global__ __launch_bounds__(256) void k_lif1(const float* __restrict__ cur1,
                                              const float* __restrict__ b1,
                                              unsigned long long* __restrict__ spk_bits,
                                              int* __restrict__ nh,
                                              int* __restrict__ hlist) {
    const int idx = blockIdx.x * 256 + threadIdx.x;   // b*128+h
    const int b = idx >> 7, h = idx & 127;
    const double b1v = (double)b1[h];
    double mem = 0.0;
    bool flagged = false;
    for (int t = 0; t < T_STEPS; ++t) {
        const double cur = (double)cur1[(size_t)t * 16384 + idx] + b1v;
        const double rst = (mem > 1.0) ? 1.0 : 0.0;
        mem = fma(0.9, mem, cur) - rst;               // EXACT form replicated in k_fixB
        const bool spk = (mem > 1.0);
        const unsigned long long m = __ballot(spk);
        if ((threadIdx.x & 63) == 0)
            spk_bits[((size_t)t * B_SZ + b) * 2 + ((h >> 6) & 1)] = m;
        if (!flagged && fabs(mem - 1.0) < FLAG_WINDOW) {
            flagged = true;
            int s = atomicAdd(&nh[b], 1);             // s < 128 structurally
            hlist[b * 128 + s] = h;
        }
    }
}

// ---------------- K4: cur2[t][b][o] = sum_{h set} W2[o][h] + b2[o] (fp64, from bitmasks) ----------------
__global__ __launch_bounds__(256) void k_cur2(const unsigned long long* __restrict__ bits,
                                              const float* __restrict__ W2,
                                              const float* __restrict__ b2,
                                              double* __restrict__ cur2) {
    __shared__ float w2s[256];
    w2s[threadIdx.x] = W2[threadIdx.x];
    __syncthreads();
    const int pair = blockIdx.x * 256 + threadIdx.x;  // t*128+b, grid 128 blocks
    unsigned long long m0 = bits[(size_t)pair * 2];
    unsigned long long m1 = bits[(size_t)pair * 2 + 1];
    double v0 = (double)b2[0], v1 = (double)b2[1];
    while (m0) {
        const int i = __ffsll((long long)m0) - 1; m0 &= m0 - 1;
        v0 += (double)w2s[i]; v1 += (double)w2s[128 + i];
    }
    while (m1) {
        const int i = __ffsll((long long)m1) - 1; m1 &= m1 - 1;
        v0 += (double)w2s[64 + i]; v1 += (double)w2s[192 + i];
    }
    cur2[(size_t)pair * 2]     = v0;
    cur2[(size_t)pair * 2 + 1] = v1;
}

// ---------------- K5a: exact fp64 dots for flagged neurons ----------------
// Block = (b, t-chunk of 16). Flagged W1 rows staged in LDS (CHUNK at a time);
// wave w handles t = tch*16 + w*4 + tt, lanes k-parallel, shuffle-reduce fp64.
__global__ __launch_bounds__(256) void k_fixA(const float* __restrict__ x,
                                              const float* __restrict__ W1,
                                              const int* __restrict__ nh,
                                              const int* __restrict__ hlist,
                                              double* __restrict__ cur_fix) {
    const int b   = blockIdx.x >> 4;
    const int tch = blockIdx.x & 15;
    const int n   = nh[b];
    if (n == 0) return;

    __shared__ float w1s[CHUNK * F_SZ];   // 120 KB
    const int tid  = threadIdx.x;
    const int wv   = tid >> 6;
    const int lane = tid & 63;

    for (int c0 = 0; c0 < n; c0 += CHUNK) {
        const int nc = (n - c0 < CHUNK) ? (n - c0) : CHUNK;
        __syncthreads();
        for (int r = 0; r < nc; ++r) {
            const int h = hlist[b * 128 + c0 + r];
            const float4* src = (const float4*)W1 + (size_t)h * F4;
            float4* dst = (float4*)(w1s + r * F_SZ);
            for (int c = tid; c < F4; c += 256) dst[c] = src[c];
        }
        __syncthreads();

        #pragma unroll 1
        for (int tt = 0; tt < 4; ++tt) {
            const int t = tch * 16 + wv * 4 + tt;
            float4 xv[10];
            const float4* xb = (const float4*)x + ((size_t)b * T_STEPS + t) * F4;
            #pragma unroll
            for (int j = 0; j < 10; ++j) {
                const int c = lane + 64 * j;
                xv[j] = (c < F4) ? xb[c] : make_float4(0.f, 0.f, 0.f, 0.f);
            }
            for (int s = 0; s < nc; ++s) {
                const float* wr = w1s + s * F_SZ;
                double p = 0.0;
                #pragma unroll
                for (int j = 0; j < 10; ++j) {
                    const int c = lane + 64 * j;
                    if (c < F4) {
                        const float4 w4 = *(const float4*)(wr + c * 4);
                        p = fma((double)xv[j].x, (double)w4.x, p);
                        p = fma((double)xv[j].y, (double)w4.y, p);
                        p = fma((double)xv[j].z, (double)w4.z, p);
                        p = fma((double)xv[j].w, (double)w4.w, p);
                    }
                }
                #pragma unroll
                for (int off = 32; off >= 1; off >>= 1) p += __shfl_down(p, off);
                if (lane == 0)
                    cur_fix[((size_t)b * 128 + c0 + s) * T_STEPS + t] = p;
            }
        }
    }
}

// ---------------- K5b: rerun approx+exact chains for flags; patch cur2 where spikes differ ----------------
__global__ __launch_bounds__(128) void k_fixB(const float* __restrict__ cur1,
                                              const double* __restrict__ cur_fix,
                                              const float* __restrict__ b1,
                                              const float* __restrict__ W2,
                                              const int* __restrict__ nh,
                                              const int* __restrict__ hlist,
                                              double* __restrict__ cur2) {
    const int b = blockIdx.x;        // 128
    const int s = threadIdx.x;       // 128
    if (s >= nh[b]) return;
    const int h = hlist[b * 128 + s];
    const double b1v = (double)b1[h];
    const double w0 = (double)W2[h], w1 = (double)W2[128 + h];
    double ma = 0.0, me = 0.0;
    for (int t = 0; t < T_STEPS; ++t) {
        const double ca = (double)cur1[((size_t)t * B_SZ + b) * H_SZ + h] + b1v;
        const double ce = cur_fix[((size_t)b * 128 + s) * T_STEPS + t] + b1v;
        const double ra = (ma > 1.0) ? 1.0 : 0.0;
        const double re = (me > 1.0) ? 1.0 : 0.0;
        ma = fma(0.9, ma, ca) - ra;   // bit-identical to k_lif1
        me = fma(0.9, me, ce) - re;
        const bool sa = (ma > 1.0), se = (me > 1.0);
        if (sa != se) {
            const double d = se ? 1.0 : -1.0;
            atomicAdd(&cur2[((size_t)t * B_SZ + b) * 2 + 0], d * w0);
            atomicAdd(&cur2[((size_t)t * B_SZ + b) * 2 + 1], d * w1);
        }
    }
}

// ---------------- K6: LIF2 (fp64) + fp32 outputs ----------------
__global__ __launch_bounds__(256) void k_lif2(const double* __restrict__ cur2,
                                              float* __restrict__ out) {
    const int tid = threadIdx.x;     // b*2+o
    double mem = 0.0;
    float* spk_out = out;
    float* mem_out = out + T_STEPS * B_SZ * O_SZ;
    #pragma unroll 8
    for (int t = 0; t < T_STEPS; ++t) {
        const double cur = cur2[t * 256 + tid];
        const double rst = (mem > 1.0) ? 1.0 : 0.0;
        mem = fma(0.9, mem, cur) - rst;
        spk_out[t * 256 + tid] = (mem > 1.0) ? 1.0f : 0.0f;
        mem_out[t * 256 + tid] = (float)mem;
    }
}

extern "C" void kernel_launch(void* const* d_in, const int* in_sizes, int n_in,
                              void* d_out, int out_size, void* d_ws, size_t ws_size,
                              hipStream_t stream) {
    const float* x  = (const float*)d_in[0];   // [128][256][2500]
    const float* W1 = (const float*)d_in[1];   // [128][2500]
    const float* b1 = (const float*)d_in[2];   // [128]
    const float* W2 = (const float*)d_in[3];   // [2][128]
    const float* b2 = (const float*)d_in[4];   // [2]
    float* out = (float*)d_out;                // 131072 floats

    char* ws = (char*)d_ws;
    float*  cur1     = (float*)ws;                          // 16,777,216 B
    float*  W1T      = (float*)(ws + 16777216);             //  1,280,000 B
    double* cur2     = (double*)(ws + 18057216);            //    524,288 B
    double* cur_fix  = (double*)(ws + 18581504);            // 33,554,432 B
    int*    nh       = (int*)(ws + 52135936);               //        512 B
    int*    hlist    = (int*)(ws + 52136448);               //     65,536 B
    unsigned long long* spk_bits = (unsigned long long*)(ws + 52201984); // 524,288 B
    // total ws use: 52,726,272 B

    k_transpose<<<1250, 256, 0, stream>>>(W1, W1T, nh);
    k_gemm<<<512, 256, 0, stream>>>(x, W1T, cur1);
    k_lif1<<<64, 256, 0, stream>>>(cur1, b1, spk_bits, nh, hlist);
    k_cur2<<<128, 256, 0, stream>>>(spk_bits, W2, b2, cur2);
    k_fixA<<<2048, 256, 0, stream>>>(x, W1, nh, hlist, cur_fix);
    k_fixB<<<128, 128, 0, stream>>>(cur1, cur_fix, b1, W2, nh, hlist, cur2);
    k_lif2<<<1, 256, 0, stream>>>(cur2, out);
}